// Round 1
// baseline (1294.001 us; speedup 1.0000x reference)
//
#include <hip/hip_runtime.h>
#include <hip/hip_bf16.h>

#define NIN  512
#define NHID 256
#define NOUT 64
#define HOPS 10

__device__ __forceinline__ unsigned short f2bf(float f) {
    unsigned u = __float_as_uint(f);
    u += 0x7FFFu + ((u >> 16) & 1u);            // RNE
    return (unsigned short)(u >> 16);
}
__device__ __forceinline__ float bf2f(unsigned short h) {
    return __uint_as_float(((unsigned)h) << 16);
}

// ---------------------------------------------------------------------------
// Fused MLP: h0 = relu(x@W1^T + b1)@W2^T + b2
// Also writes hop-0 attention contribution: out = sigmoid(h0 . s) * h0
// Block: 256 threads, 64-node tile. LDS: As/Bs staging + bf16 h1 tile.
// ---------------------------------------------------------------------------
__global__ __launch_bounds__(256, 2) void mlp_kernel(
    const float* __restrict__ x, const float* __restrict__ W1,
    const float* __restrict__ b1, const float* __restrict__ W2,
    const float* __restrict__ b2, const float* __restrict__ s,
    float* __restrict__ h_out, float* __restrict__ out, int n)
{
    __shared__ float R1[5440];                 // As[16][68]+Bs[16][260]  OR  H0[64][68]+RED[64][17]
    __shared__ unsigned short H1[NHID][72];    // h1 tile, bf16, transposed [j][m]
    float* As  = R1;               // [16][68]  x^T tile (k-major)
    float* Bs  = R1 + 16 * 68;     // [16][260] W1 tile (k-major)
    float* H0  = R1;               // [64][68]  h0 tile (reuses As/Bs space)
    float* RED = R1 + 64 * 68;     // [64][17]  attention partials

    const int t    = threadIdx.x;
    const int row0 = blockIdx.x * 64;

    // staging mapping: thread -> (row lm, k-quad lk4) for x; row t of W1
    const int lm  = t >> 2;
    const int lk4 = (t & 3) << 2;
    int xrow = row0 + lm; if (xrow >= n) xrow = n - 1;
    const float* xp = x  + (size_t)xrow * NIN;
    const float* wp = W1 + (size_t)t    * NIN;

    // compute mapping phase1: 16 (tm) x 16 (tn) threads; micro-tile 4m x 16n
    const int tm = t & 15, tn = t >> 4;
    const int m0 = tm << 2, n0 = tn << 4;

    // prefetch k-tile 0 into registers
    float4 xa = *(const float4*)(xp + lk4);
    float4 wb[4];
    #pragma unroll
    for (int q = 0; q < 4; ++q) wb[q] = *(const float4*)(wp + (q << 2));

    float acc[4][16];
    #pragma unroll
    for (int mi = 0; mi < 4; ++mi)
        #pragma unroll
        for (int ni = 0; ni < 16; ++ni) acc[mi][ni] = 0.f;

    #pragma unroll 1
    for (int kt = 0; kt < NIN / 16; ++kt) {
        __syncthreads();
        As[(lk4 + 0) * 68 + lm] = xa.x;
        As[(lk4 + 1) * 68 + lm] = xa.y;
        As[(lk4 + 2) * 68 + lm] = xa.z;
        As[(lk4 + 3) * 68 + lm] = xa.w;
        #pragma unroll
        for (int q = 0; q < 4; ++q) {
            Bs[(4 * q + 0) * 260 + t] = wb[q].x;
            Bs[(4 * q + 1) * 260 + t] = wb[q].y;
            Bs[(4 * q + 2) * 260 + t] = wb[q].z;
            Bs[(4 * q + 3) * 260 + t] = wb[q].w;
        }
        __syncthreads();
        if (kt + 1 < NIN / 16) {                       // prefetch next k-tile
            const int k0 = (kt + 1) << 4;
            xa = *(const float4*)(xp + k0 + lk4);
            #pragma unroll
            for (int q = 0; q < 4; ++q) wb[q] = *(const float4*)(wp + k0 + (q << 2));
        }
        #pragma unroll
        for (int kk = 0; kk < 16; ++kk) {
            float4 av = *(const float4*)&As[kk * 68 + m0];
            const float am[4] = {av.x, av.y, av.z, av.w};
            float b[16];
            #pragma unroll
            for (int q = 0; q < 4; ++q) {
                float4 bv = *(const float4*)&Bs[kk * 260 + n0 + (q << 2)];
                b[q * 4 + 0] = bv.x; b[q * 4 + 1] = bv.y;
                b[q * 4 + 2] = bv.z; b[q * 4 + 3] = bv.w;
            }
            #pragma unroll
            for (int mi = 0; mi < 4; ++mi)
                #pragma unroll
                for (int ni = 0; ni < 16; ++ni)
                    acc[mi][ni] = fmaf(am[mi], b[ni], acc[mi][ni]);
        }
    }

    // bias + relu -> H1 (bf16, [j][m] transposed)
    #pragma unroll
    for (int ni = 0; ni < 16; ++ni) {
        const float bv = b1[n0 + ni];
        unsigned short e0 = f2bf(fmaxf(acc[0][ni] + bv, 0.f));
        unsigned short e1 = f2bf(fmaxf(acc[1][ni] + bv, 0.f));
        unsigned short e2 = f2bf(fmaxf(acc[2][ni] + bv, 0.f));
        unsigned short e3 = f2bf(fmaxf(acc[3][ni] + bv, 0.f));
        *(unsigned*)&H1[n0 + ni][m0]     = (unsigned)e0 | ((unsigned)e1 << 16);
        *(unsigned*)&H1[n0 + ni][m0 + 2] = (unsigned)e2 | ((unsigned)e3 << 16);
    }
    __syncthreads();

    // phase 2: h0[m][o] = sum_j h1[m][j] * W2[o][j];  thread: 4m x 4o
    const int o0 = tn << 2;
    float acc2[4][4];
    #pragma unroll
    for (int mi = 0; mi < 4; ++mi)
        #pragma unroll
        for (int oi = 0; oi < 4; ++oi) acc2[mi][oi] = 0.f;

    #pragma unroll 2
    for (int j4 = 0; j4 < NHID / 4; ++j4) {
        float a[4][4];                                  // [dj][mi]
        #pragma unroll
        for (int dj = 0; dj < 4; ++dj) {
            ushort4 av = *(const ushort4*)&H1[j4 * 4 + dj][m0];
            a[dj][0] = bf2f(av.x); a[dj][1] = bf2f(av.y);
            a[dj][2] = bf2f(av.z); a[dj][3] = bf2f(av.w);
        }
        #pragma unroll
        for (int oi = 0; oi < 4; ++oi) {
            float4 wv = *(const float4*)(W2 + (size_t)(o0 + oi) * NHID + j4 * 4);
            #pragma unroll
            for (int mi = 0; mi < 4; ++mi)
                acc2[mi][oi] += a[0][mi] * wv.x + a[1][mi] * wv.y
                              + a[2][mi] * wv.z + a[3][mi] * wv.w;
        }
    }

    // bias + attention partials; spill tile to LDS (reuses As/Bs region)
    float p[4];
    #pragma unroll
    for (int mi = 0; mi < 4; ++mi) {
        p[mi] = 0.f;
        #pragma unroll
        for (int oi = 0; oi < 4; ++oi) {
            acc2[mi][oi] += b2[o0 + oi];
            p[mi] += acc2[mi][oi] * s[o0 + oi];
        }
    }
    #pragma unroll
    for (int mi = 0; mi < 4; ++mi) {
        #pragma unroll
        for (int oi = 0; oi < 4; ++oi)
            H0[(m0 + mi) * 68 + o0 + oi] = acc2[mi][oi];
        RED[(m0 + mi) * 17 + tn] = p[mi];
    }
    __syncthreads();

    // epilogue: thread -> (row m, quarter q); sigmoid + coalesced stores
    {
        const int m = t >> 2, q = t & 3;
        float sum = RED[m * 17 + (q << 2) + 0] + RED[m * 17 + (q << 2) + 1]
                  + RED[m * 17 + (q << 2) + 2] + RED[m * 17 + (q << 2) + 3];
        sum += __shfl_xor(sum, 1);
        sum += __shfl_xor(sum, 2);
        const float sig = 1.f / (1.f + expf(-sum));
        const int grow = row0 + m;
        if (grow < n) {
            float* hp = h_out + (size_t)grow * NOUT + (q << 4);
            float* op = out   + (size_t)grow * NOUT + (q << 4);
            #pragma unroll
            for (int i = 0; i < 16; i += 4) {
                float4 hv = *(const float4*)&H0[m * 68 + (q << 4) + i];
                *(float4*)(hp + i) = hv;
                float4 ov; ov.x = sig * hv.x; ov.y = sig * hv.y;
                ov.z = sig * hv.z; ov.w = sig * hv.w;
                *(float4*)(op + i) = ov;
            }
        }
    }
}

// ---------------------------------------------------------------------------
// CSR build: degree count -> hierarchical exclusive scan -> scatter
// ---------------------------------------------------------------------------
__global__ void k_count(const int* __restrict__ erow, int* __restrict__ deg, int e) {
    int i = blockIdx.x * 256 + threadIdx.x;
    if (i < e) atomicAdd(&deg[erow[i]], 1);
}

__global__ void k_scan1(const int* __restrict__ deg, int* __restrict__ rp,
                        int* __restrict__ bsum, int nv) {
    __shared__ int sm[256];
    const int i = blockIdx.x * 256 + threadIdx.x;
    const int v = (i < nv) ? deg[i] : 0;
    sm[threadIdx.x] = v;
    __syncthreads();
    for (int off = 1; off < 256; off <<= 1) {
        int tv = (threadIdx.x >= off) ? sm[threadIdx.x - off] : 0;
        __syncthreads();
        sm[threadIdx.x] += tv;
        __syncthreads();
    }
    if (i < nv) rp[i] = sm[threadIdx.x] - v;           // exclusive within block
    if (threadIdx.x == 255) bsum[blockIdx.x] = sm[255];
}

__global__ void k_scan2(int* __restrict__ bsum, int nb) {
    __shared__ int sm[512];
    const int tid = threadIdx.x;
    const int v = (tid < nb) ? bsum[tid] : 0;
    sm[tid] = v;
    __syncthreads();
    for (int off = 1; off < 512; off <<= 1) {
        int tv = (tid >= off) ? sm[tid - off] : 0;
        __syncthreads();
        sm[tid] += tv;
        __syncthreads();
    }
    if (tid < nb) bsum[tid] = sm[tid] - v;             // exclusive block offsets
}

__global__ void k_scan3(int* __restrict__ rp, int* __restrict__ cur,
                        const int* __restrict__ bsum, int nv, int e) {
    const int i = blockIdx.x * 256 + threadIdx.x;
    if (i < nv) {
        const int vv = rp[i] + bsum[blockIdx.x];
        rp[i]  = vv;
        cur[i] = vv;
    }
    if (i == 0) rp[nv] = e;
}

__global__ void k_scatter(const int* __restrict__ erow, const int* __restrict__ ecol,
                          const float* __restrict__ ev, int* __restrict__ cur,
                          int* __restrict__ ccol, float* __restrict__ cval, int e) {
    const int i = blockIdx.x * 256 + threadIdx.x;
    if (i < e) {
        const int r = erow[i];
        const int p = atomicAdd(&cur[r], 1);
        ccol[p] = ecol[i];
        cval[p] = ev[i];
    }
}

// ---------------------------------------------------------------------------
// One propagation hop (pull, CSR): h_out[n] = sum_{e in row n} val_e * h_in[col_e]
// Fused attention epilogue: out[n] += sigmoid(h_out[n] . s) * h_out[n]
// One wave (64 lanes = 64 features) per node.
// ---------------------------------------------------------------------------
__global__ __launch_bounds__(256) void hop_kernel(
    const float* __restrict__ h_in, float* __restrict__ h_out,
    const int* __restrict__ row_ptr, const int* __restrict__ csr_col,
    const float* __restrict__ csr_val, const float* __restrict__ s,
    float* __restrict__ out, int n)
{
    const int lane = threadIdx.x & 63;
    const int node = (blockIdx.x * 256 + threadIdx.x) >> 6;
    if (node >= n) return;
    const int start = row_ptr[node];
    const int end   = row_ptr[node + 1];
    float a0 = 0.f, a1 = 0.f, a2 = 0.f, a3 = 0.f;
    for (int base = start; base < end; base += 64) {
        const int idx = base + lane;
        int c = 0; float v = 0.f;
        if (idx < end) { c = csr_col[idx]; v = csr_val[idx]; }
        const int cnt = min(64, end - base);
        int e = 0;
        for (; e + 4 <= cnt; e += 4) {           // 4 gathers in flight
            int   c0 = __shfl(c, e),     c1 = __shfl(c, e + 1);
            int   c2 = __shfl(c, e + 2), c3 = __shfl(c, e + 3);
            float v0 = __shfl(v, e),     v1 = __shfl(v, e + 1);
            float v2 = __shfl(v, e + 2), v3 = __shfl(v, e + 3);
            float g0 = h_in[c0 * 64 + lane];
            float g1 = h_in[c1 * 64 + lane];
            float g2 = h_in[c2 * 64 + lane];
            float g3 = h_in[c3 * 64 + lane];
            a0 = fmaf(v0, g0, a0); a1 = fmaf(v1, g1, a1);
            a2 = fmaf(v2, g2, a2); a3 = fmaf(v3, g3, a3);
        }
        for (; e < cnt; ++e) {
            int cc = __shfl(c, e); float vv = __shfl(v, e);
            a0 = fmaf(vv, h_in[cc * 64 + lane], a0);
        }
    }
    const float acc = (a0 + a1) + (a2 + a3);
    h_out[node * 64 + lane] = acc;
    float tv = acc * s[lane];
    #pragma unroll
    for (int off = 32; off > 0; off >>= 1) tv += __shfl_xor(tv, off);
    const float sig = 1.f / (1.f + expf(-tv));
    out[node * 64 + lane] += sig * acc;
}

// ---------------------------------------------------------------------------
extern "C" void kernel_launch(void* const* d_in, const int* in_sizes, int n_in,
                              void* d_out, int out_size, void* d_ws, size_t ws_size,
                              hipStream_t stream)
{
    const float* x  = (const float*)d_in[0];
    const int*   er = (const int*)  d_in[1];
    const int*   ec = (const int*)  d_in[2];
    const float* ev = (const float*)d_in[3];
    const float* W1 = (const float*)d_in[4];
    const float* b1 = (const float*)d_in[5];
    const float* W2 = (const float*)d_in[6];
    const float* b2 = (const float*)d_in[7];
    const float* s  = (const float*)d_in[8];
    float* out = (float*)d_out;

    const int n = in_sizes[0] / NIN;   // 100000
    const int e = in_sizes[1];         // 1600000

    // workspace carve (256B aligned): ~65.3 MB total
    char* w = (char*)d_ws;
    auto carve = [&](size_t bytes) { char* p = w; w += (bytes + 255) & ~(size_t)255; return p; };
    float* h_a  = (float*)carve((size_t)n * NOUT * 4);
    float* h_b  = (float*)carve((size_t)n * NOUT * 4);
    int*   deg  = (int*)  carve((size_t)n * 4);
    int*   rp   = (int*)  carve(((size_t)n + 1) * 4);
    int*   cur  = (int*)  carve((size_t)n * 4);
    int*   ccol = (int*)  carve((size_t)e * 4);
    float* cval = (float*)carve((size_t)e * 4);
    int*   bsum = (int*)  carve(1024 * 4);

    hipMemsetAsync(deg, 0, (size_t)n * 4, stream);

    const int mgrid = (n + 63) / 64;
    mlp_kernel<<<mgrid, 256, 0, stream>>>(x, W1, b1, W2, b2, s, h_a, out, n);

    const int eg = (e + 255) / 256;
    const int nb = (n + 255) / 256;
    k_count  <<<eg, 256, 0, stream>>>(er, deg, e);
    k_scan1  <<<nb, 256, 0, stream>>>(deg, rp, bsum, n);
    k_scan2  <<<1, 512, 0, stream>>>(bsum, nb);
    k_scan3  <<<nb, 256, 0, stream>>>(rp, cur, bsum, n, e);
    k_scatter<<<eg, 256, 0, stream>>>(er, ec, ev, cur, ccol, cval, e);

    float* hi = h_a; float* ho = h_b;
    const int hgrid = (n + 3) / 4;
    for (int hop = 0; hop < HOPS; ++hop) {
        hop_kernel<<<hgrid, 256, 0, stream>>>(hi, ho, rp, ccol, cval, s, out, n);
        float* tmp = hi; hi = ho; ho = tmp;
    }
}

// Round 4
// 945.450 us; speedup vs baseline: 1.3687x; 1.3687x over previous
//
#include <hip/hip_runtime.h>
#include <hip/hip_bf16.h>

#define NIN  512
#define NHID 256
#define NOUT 64
#define HOPS 10

typedef __attribute__((ext_vector_type(8))) short bf16x8;
typedef __attribute__((ext_vector_type(4))) float f32x4;

__device__ __forceinline__ unsigned short f2bf(float f) {
    unsigned u = __float_as_uint(f);
    u += 0x7FFFu + ((u >> 16) & 1u);            // RNE
    return (unsigned short)(u >> 16);
}
__device__ __forceinline__ unsigned pk2(float a, float b) {
    return (unsigned)f2bf(a) | ((unsigned)f2bf(b) << 16);
}

// ---------------------------------------------------------------------------
// Pre-permute W1, W2 into MFMA A-fragment order (bf16).
// W1f (GEMM1 A, kappa1(g,j) = g*8+j): frag fi = kt*16 + w*4 + hf; elem (l,j):
//      W1[(w*64 + hf*16 + (l&15))*512 + kt*32 + (l>>4)*8 + j]
// W2f (GEMM2 A, kappa2(g,j) = (j>>2)*16 + g*4 + (j&3)): frag fi = c*4 + nf2:
//      W2[(nf2*16 + (l&15))*256 + c*32 + (j>>2)*16 + (l>>4)*4 + (j&3)]
// ---------------------------------------------------------------------------
__global__ void k_preconv(const float* __restrict__ W1, const float* __restrict__ W2,
                          unsigned short* __restrict__ W1f, unsigned short* __restrict__ W2f)
{
    const int i = blockIdx.x * 256 + threadIdx.x;
    if (i < NHID * NIN) {
        const int j = i & 7, l = (i >> 3) & 63, fi = i >> 9;
        const int ks = fi >> 4, w = (fi >> 2) & 3, nf = fi & 3;
        const int col = w * 64 + nf * 16 + (l & 15);
        const int k   = ks * 32 + ((l >> 4) << 3) + j;
        W1f[i] = f2bf(W1[col * NIN + k]);
    }
    if (i < NOUT * NHID) {
        const int j = i & 7, l = (i >> 3) & 63, fi = i >> 9;
        const int ks = fi >> 2, nf = fi & 3;
        const int col = nf * 16 + (l & 15);
        const int k   = ks * 32 + ((j >> 2) << 4) + ((l >> 4) << 2) + (j & 3);
        W2f[i] = f2bf(W2[col * NHID + k]);
    }
}

// ---------------------------------------------------------------------------
// Fused MFMA MLP (operand-swapped): h1^T = W1 @ x^T, then h0^T = W2 @ h1^T.
// GEMM1's D (lane = node col) is already in GEMM2's B-fragment lane layout;
// k-slots line up via kappa2 = (j>>2)*16 + (l>>4)*4 + (j&3) (baked into W2f).
// W1 fragments are read DIRECTLY from global per-lane (each wave consumes
// exactly the fragments it would have staged -> no LDS, no global_load_lds,
// no async pipeline). Only the x tile goes through LDS (reg -> ds_write ->
// barrier -> ds_read, conventional dbuf).
// + hop-0 attention epilogue: out = sigmoid(h0 . s) * h0
// ---------------------------------------------------------------------------
__global__ __launch_bounds__(256, 2) void mlp_kernel(
    const float* __restrict__ x, const unsigned short* __restrict__ W1f,
    const float* __restrict__ b1, const unsigned short* __restrict__ W2f,
    const float* __restrict__ b2, const float* __restrict__ s,
    float* __restrict__ h_out, float* __restrict__ out, int n)
{
    // LDS overlay: [0,32768)        B2L [4][8][64][8] h1^T frags (GEMM2 phase)
    //              [32768, +8192)   BX  [2][4][64][8] x frags (GEMM1 dbuf)
    //              [32768, +17408)  H0L [64][68] f32 (epilogue, after BX dead)
    //              [50176, +256)    SIGL[64] f32
    __shared__ __align__(16) char smem[50432];
    short* B2L  = (short*)smem;
    short* BX   = (short*)(smem + 32768);
    float* H0L  = (float*)(smem + 32768);
    float* SIGL = (float*)(smem + 50176);

    const int t  = threadIdx.x;
    const int w  = t >> 6, lz = t & 63;
    const int row0 = blockIdx.x * 64;

    // x staging mapping: thread -> (row srow, float4-quads q4a/q4b)
    const int srow = t >> 2;
    int xrow = row0 + srow; if (xrow >= n) xrow = n - 1;
    const float4* xp = (const float4*)(x + (size_t)xrow * NIN);
    const int q4a = t & 3, q4b = (t & 3) + 4;

    f32x4 acc[4][4];                       // [node-frag nfn][hid-frag hf]
    #pragma unroll
    for (int a = 0; a < 4; ++a)
        #pragma unroll
        for (int b = 0; b < 4; ++b) acc[a][b] = (f32x4)(0.f);

    auto xwrite = [&](int b, float4 va, float4 vb) {  // cvt + frag-ordered write
        unsigned long long pa = (unsigned long long)pk2(va.x, va.y)
                              | ((unsigned long long)pk2(va.z, va.w) << 32);
        unsigned long long pb = (unsigned long long)pk2(vb.x, vb.y)
                              | ((unsigned long long)pk2(vb.z, vb.w) << 32);
        *(unsigned long long*)&BX[(((((b << 2) + (srow >> 4)) << 6)
            + ((srow & 15) | ((q4a >> 1) << 4))) << 3) + ((q4a & 1) << 2)] = pa;
        *(unsigned long long*)&BX[(((((b << 2) + (srow >> 4)) << 6)
            + ((srow & 15) | ((q4b >> 1) << 4))) << 3) + ((q4b & 1) << 2)] = pb;
    };
    auto compute = [&](int b, int kt) {
        bf16x8 xf[4], wf[4];
        #pragma unroll
        for (int nfn = 0; nfn < 4; ++nfn)
            xf[nfn] = *(const bf16x8*)&BX[((((b << 2) + nfn) << 6) + lz) << 3];
        const unsigned short* wp = W1f + ((size_t)kt << 13) + (w << 11) + (lz << 3);
        #pragma unroll
        for (int hf = 0; hf < 4; ++hf)
            wf[hf] = *(const bf16x8*)(wp + (hf << 9));   // direct global, coalesced
        #pragma unroll
        for (int nfn = 0; nfn < 4; ++nfn)
            #pragma unroll
            for (int hf = 0; hf < 4; ++hf)
                acc[nfn][hf] = __builtin_amdgcn_mfma_f32_16x16x32_bf16(
                    wf[hf], xf[nfn], acc[nfn][hf], 0, 0, 0);   // A=W1, B=x^T
    };

    // ---- GEMM1 main loop (conventional dbuf, one barrier per k-tile) -----
    {
        float4 xa = xp[q4a], xb = xp[q4b];
        xwrite(0, xa, xb);
    }
    __syncthreads();

    #pragma unroll 1
    for (int kt = 0; kt < 16; ++kt) {
        const int b = kt & 1;
        float4 nxa, nxb;
        if (kt < 15) {
            nxa = xp[((kt + 1) << 3) + q4a];
            nxb = xp[((kt + 1) << 3) + q4b];
        }
        compute(b, kt);
        if (kt < 15) xwrite(b ^ 1, nxa, nxb);
        __syncthreads();
    }

    // ---- bias + relu + in-register repack -> B2L (h1^T B-fragments) -----
    // lane lz holds h1^T[hid = w*64 + hf*16 + (lz>>4)*4 + r][node = nfn*16 + (lz&15)]
    // B2L frag (nfn, c=2w+cl) slot (l, j) = h1[node][c*32 + (j>>2)*16 + (l>>4)*4 + (j&3)]
    {
        float4 b1q[4];
        #pragma unroll
        for (int hf = 0; hf < 4; ++hf)
            b1q[hf] = *(const float4*)(b1 + (w << 6) + (hf << 4) + ((lz >> 4) << 2));
        #pragma unroll
        for (int nfn = 0; nfn < 4; ++nfn) {
            #pragma unroll
            for (int cl = 0; cl < 2; ++cl) {
                f32x4 a0 = acc[nfn][2 * cl], a1 = acc[nfn][2 * cl + 1];
                float4 c0 = b1q[2 * cl], c1 = b1q[2 * cl + 1];
                uint4 pv;
                pv.x = pk2(fmaxf(a0.x + c0.x, 0.f), fmaxf(a0.y + c0.y, 0.f));
                pv.y = pk2(fmaxf(a0.z + c0.z, 0.f), fmaxf(a0.w + c0.w, 0.f));
                pv.z = pk2(fmaxf(a1.x + c1.x, 0.f), fmaxf(a1.y + c1.y, 0.f));
                pv.w = pk2(fmaxf(a1.z + c1.z, 0.f), fmaxf(a1.w + c1.w, 0.f));
                *(uint4*)&B2L[((((nfn << 3) + (w << 1) + cl) << 6) + lz) << 3] = pv;
            }
        }
    }
    __syncthreads();

    // ---- GEMM2: h0^T = W2 @ h1^T; wave w -> node block w (nodes w*16..+15)
    f32x4 acc2[4];
    #pragma unroll
    for (int nf2 = 0; nf2 < 4; ++nf2) acc2[nf2] = (f32x4)(0.f);

    #pragma unroll
    for (int c = 0; c < 8; ++c) {
        bf16x8 hfrag = *(const bf16x8*)&B2L[((((w << 3) + c) << 6) + lz) << 3];
        #pragma unroll
        for (int nf2 = 0; nf2 < 4; ++nf2) {
            bf16x8 wfrag = *(const bf16x8*)(W2f + (((c << 2) + nf2) << 9) + (lz << 3));
            acc2[nf2] = __builtin_amdgcn_mfma_f32_16x16x32_bf16(
                wfrag, hfrag, acc2[nf2], 0, 0, 0);             // A=W2, B=h1^T
        }
    }

    // ---- epilogue: bias, attention dot, sigmoid, LDS reshape, stores -----
    // lane lz: h0[node = w*16 + (lz&15)][outf = nf2*16 + (lz>>4)*4 + r]
    {
        float dot = 0.f;
        #pragma unroll
        for (int nf2 = 0; nf2 < 4; ++nf2) {
            float4 bq = *(const float4*)(b2 + (nf2 << 4) + ((lz >> 4) << 2));
            float4 qv = *(const float4*)(s  + (nf2 << 4) + ((lz >> 4) << 2));
            acc2[nf2].x += bq.x; acc2[nf2].y += bq.y;
            acc2[nf2].z += bq.z; acc2[nf2].w += bq.w;
            dot += acc2[nf2].x * qv.x + acc2[nf2].y * qv.y
                 + acc2[nf2].z * qv.z + acc2[nf2].w * qv.w;
        }
        dot += __shfl_xor(dot, 16);
        dot += __shfl_xor(dot, 32);
        const float sig = 1.f / (1.f + expf(-dot));
        if (lz < 16) SIGL[(w << 4) + lz] = sig;
        const int mloc = (w << 4) + (lz & 15);
        #pragma unroll
        for (int nf2 = 0; nf2 < 4; ++nf2) {
            float4 hv; hv.x = acc2[nf2].x; hv.y = acc2[nf2].y;
            hv.z = acc2[nf2].z; hv.w = acc2[nf2].w;
            *(float4*)&H0L[mloc * 68 + (nf2 << 4) + ((lz >> 4) << 2)] = hv;
        }
    }
    __syncthreads();

    {
        const int m = t >> 2, q = t & 3;
        const int g = row0 + m;
        if (g < n) {
            const float sigv = SIGL[m];
            float* hp = h_out + (size_t)g * NOUT + (q << 4);
            float* op = out   + (size_t)g * NOUT + (q << 4);
            #pragma unroll
            for (int i = 0; i < 16; i += 4) {
                float4 hv = *(const float4*)&H0L[m * 68 + (q << 4) + i];
                *(float4*)(hp + i) = hv;
                float4 ov; ov.x = sigv * hv.x; ov.y = sigv * hv.y;
                ov.z = sigv * hv.z; ov.w = sigv * hv.w;
                *(float4*)(op + i) = ov;
            }
        }
    }
}

// ---------------------------------------------------------------------------
// CSR build: degree count -> hierarchical exclusive scan -> scatter
// ---------------------------------------------------------------------------
__global__ void k_count(const int* __restrict__ erow, int* __restrict__ deg, int e) {
    int i = blockIdx.x * 256 + threadIdx.x;
    if (i < e) atomicAdd(&deg[erow[i]], 1);
}

__global__ void k_scan1(const int* __restrict__ deg, int* __restrict__ rp,
                        int* __restrict__ bsum, int nv) {
    __shared__ int sm[256];
    const int i = blockIdx.x * 256 + threadIdx.x;
    const int v = (i < nv) ? deg[i] : 0;
    sm[threadIdx.x] = v;
    __syncthreads();
    for (int off = 1; off < 256; off <<= 1) {
        int tv = (threadIdx.x >= off) ? sm[threadIdx.x - off] : 0;
        __syncthreads();
        sm[threadIdx.x] += tv;
        __syncthreads();
    }
    if (i < nv) rp[i] = sm[threadIdx.x] - v;
    if (threadIdx.x == 255) bsum[blockIdx.x] = sm[255];
}

__global__ void k_scan2(int* __restrict__ bsum, int nb) {
    __shared__ int sm[512];
    const int tid = threadIdx.x;
    const int v = (tid < nb) ? bsum[tid] : 0;
    sm[tid] = v;
    __syncthreads();
    for (int off = 1; off < 512; off <<= 1) {
        int tv = (tid >= off) ? sm[tid - off] : 0;
        __syncthreads();
        sm[tid] += tv;
        __syncthreads();
    }
    if (tid < nb) bsum[tid] = sm[tid] - v;
}

__global__ void k_scan3(int* __restrict__ rp, int* __restrict__ cur,
                        const int* __restrict__ bsum, int nv, int e) {
    const int i = blockIdx.x * 256 + threadIdx.x;
    if (i < nv) {
        const int vv = rp[i] + bsum[blockIdx.x];
        rp[i]  = vv;
        cur[i] = vv;
    }
    if (i == 0) rp[nv] = e;
}

__global__ void k_scatter(const int* __restrict__ erow, const int* __restrict__ ecol,
                          const float* __restrict__ ev, int* __restrict__ cur,
                          int* __restrict__ ccol, float* __restrict__ cval, int e) {
    const int i = blockIdx.x * 256 + threadIdx.x;
    if (i < e) {
        const int r = erow[i];
        const int p = atomicAdd(&cur[r], 1);
        ccol[p] = ecol[i];
        cval[p] = ev[i];
    }
}

// ---------------------------------------------------------------------------
// One propagation hop (pull, CSR) + fused attention epilogue.
// ---------------------------------------------------------------------------
__global__ __launch_bounds__(256) void hop_kernel(
    const float* __restrict__ h_in, float* __restrict__ h_out,
    const int* __restrict__ row_ptr, const int* __restrict__ csr_col,
    const float* __restrict__ csr_val, const float* __restrict__ s,
    float* __restrict__ out, int n)
{
    const int lane = threadIdx.x & 63;
    const int node = (blockIdx.x * 256 + threadIdx.x) >> 6;
    if (node >= n) return;
    const int start = row_ptr[node];
    const int end   = row_ptr[node + 1];
    float a0 = 0.f, a1 = 0.f, a2 = 0.f, a3 = 0.f;
    for (int base = start; base < end; base += 64) {
        const int idx = base + lane;
        int c = 0; float v = 0.f;
        if (idx < end) { c = csr_col[idx]; v = csr_val[idx]; }
        const int cnt = min(64, end - base);
        int e = 0;
        for (; e + 4 <= cnt; e += 4) {
            int   c0 = __shfl(c, e),     c1 = __shfl(c, e + 1);
            int   c2 = __shfl(c, e + 2), c3 = __shfl(c, e + 3);
            float v0 = __shfl(v, e),     v1 = __shfl(v, e + 1);
            float v2 = __shfl(v, e + 2), v3 = __shfl(v, e + 3);
            float g0 = h_in[c0 * 64 + lane];
            float g1 = h_in[c1 * 64 + lane];
            float g2 = h_in[c2 * 64 + lane];
            float g3 = h_in[c3 * 64 + lane];
            a0 = fmaf(v0, g0, a0); a1 = fmaf(v1, g1, a1);
            a2 = fmaf(v2, g2, a2); a3 = fmaf(v3, g3, a3);
        }
        for (; e < cnt; ++e) {
            int cc = __shfl(c, e); float vv = __shfl(v, e);
            a0 = fmaf(vv, h_in[cc * 64 + lane], a0);
        }
    }
    const float acc = (a0 + a1) + (a2 + a3);
    h_out[node * 64 + lane] = acc;
    float tv = acc * s[lane];
    #pragma unroll
    for (int off = 32; off > 0; off >>= 1) tv += __shfl_xor(tv, off);
    const float sig = 1.f / (1.f + expf(-tv));
    out[node * 64 + lane] += sig * acc;
}

// ---------------------------------------------------------------------------
extern "C" void kernel_launch(void* const* d_in, const int* in_sizes, int n_in,
                              void* d_out, int out_size, void* d_ws, size_t ws_size,
                              hipStream_t stream)
{
    const float* x  = (const float*)d_in[0];
    const int*   er = (const int*)  d_in[1];
    const int*   ec = (const int*)  d_in[2];
    const float* ev = (const float*)d_in[3];
    const float* W1 = (const float*)d_in[4];
    const float* b1 = (const float*)d_in[5];
    const float* W2 = (const float*)d_in[6];
    const float* b2 = (const float*)d_in[7];
    const float* s  = (const float*)d_in[8];
    float* out = (float*)d_out;

    const int n = in_sizes[0] / NIN;   // 100000
    const int e = in_sizes[1];         // 1600000

    // workspace carve (256B aligned)
    char* w = (char*)d_ws;
    auto carve = [&](size_t bytes) { char* p = w; w += (bytes + 255) & ~(size_t)255; return p; };
    float* h_a  = (float*)carve((size_t)n * NOUT * 4);
    float* h_b  = (float*)carve((size_t)n * NOUT * 4);
    int*   deg  = (int*)  carve((size_t)n * 4);
    int*   rp   = (int*)  carve(((size_t)n + 1) * 4);
    int*   cur  = (int*)  carve((size_t)n * 4);
    int*   ccol = (int*)  carve((size_t)e * 4);
    float* cval = (float*)carve((size_t)e * 4);
    int*   bsum = (int*)  carve(1024 * 4);
    unsigned short* W1f = (unsigned short*)carve((size_t)NHID * NIN * 2);
    unsigned short* W2f = (unsigned short*)carve((size_t)NOUT * NHID * 2);

    hipMemsetAsync(deg, 0, (size_t)n * 4, stream);

    k_preconv<<<(NHID * NIN + 255) / 256, 256, 0, stream>>>(W1, W2, W1f, W2f);

    const int mgrid = (n + 63) / 64;
    mlp_kernel<<<mgrid, 256, 0, stream>>>(x, W1f, b1, W2f, b2, s, h_a, out, n);

    const int eg = (e + 255) / 256;
    const int nb = (n + 255) / 256;
    k_count  <<<eg, 256, 0, stream>>>(er, deg, e);
    k_scan1  <<<nb, 256, 0, stream>>>(deg, rp, bsum, n);
    k_scan2  <<<1, 512, 0, stream>>>(bsum, nb);
    k_scan3  <<<nb, 256, 0, stream>>>(rp, cur, bsum, n, e);
    k_scatter<<<eg, 256, 0, stream>>>(er, ec, ev, cur, ccol, cval, e);

    float* hi = h_a; float* ho = h_b;
    const int hgrid = (n + 3) / 4;
    for (int hop = 0; hop < HOPS; ++hop) {
        hop_kernel<<<hgrid, 256, 0, stream>>>(hi, ho, rp, ccol, cval, s, out, n);
        float* tmp = hi; hi = ho; ho = tmp;
    }
}

// Round 5
// 625.957 us; speedup vs baseline: 2.0672x; 1.5104x over previous
//
#include <hip/hip_runtime.h>
#include <hip/hip_bf16.h>

#define NIN  512
#define NHID 256
#define NOUT 64
#define HOPS 10

typedef __attribute__((ext_vector_type(8))) short bf16x8;
typedef __attribute__((ext_vector_type(4))) float f32x4;

__device__ __forceinline__ unsigned short f2bf(float f) {
    unsigned u = __float_as_uint(f);
    u += 0x7FFFu + ((u >> 16) & 1u);            // RNE
    return (unsigned short)(u >> 16);
}
__device__ __forceinline__ unsigned pk2(float a, float b) {
    return (unsigned)f2bf(a) | ((unsigned)f2bf(b) << 16);
}
__device__ __forceinline__ float bflo(unsigned g) { return __uint_as_float(g << 16); }
__device__ __forceinline__ float bfhi(unsigned g) { return __uint_as_float(g & 0xFFFF0000u); }

// ---------------------------------------------------------------------------
// Pre-permute W1, W2 into MFMA A-fragment order (bf16).  (verified R4)
// ---------------------------------------------------------------------------
__global__ void k_preconv(const float* __restrict__ W1, const float* __restrict__ W2,
                          unsigned short* __restrict__ W1f, unsigned short* __restrict__ W2f)
{
    const int i = blockIdx.x * 256 + threadIdx.x;
    if (i < NHID * NIN) {
        const int j = i & 7, l = (i >> 3) & 63, fi = i >> 9;
        const int ks = fi >> 4, w = (fi >> 2) & 3, nf = fi & 3;
        const int col = w * 64 + nf * 16 + (l & 15);
        const int k   = ks * 32 + ((l >> 4) << 3) + j;
        W1f[i] = f2bf(W1[col * NIN + k]);
    }
    if (i < NOUT * NHID) {
        const int j = i & 7, l = (i >> 3) & 63, fi = i >> 9;
        const int ks = fi >> 2, nf = fi & 3;
        const int col = nf * 16 + (l & 15);
        const int k   = ks * 32 + ((j >> 2) << 4) + ((l >> 4) << 2) + (j & 3);
        W2f[i] = f2bf(W2[col * NHID + k]);
    }
}

// ---------------------------------------------------------------------------
// Fused MFMA MLP (operand-swapped, verified R4): h1^T = W1 @ x^T, then
// h0^T = W2 @ h1^T. Outputs: bf16-packed h0 (uint[n][32], lo=even feature)
// and sig0[n] (hop-0 attention weight). No out write (deferred combine).
// ---------------------------------------------------------------------------
__global__ __launch_bounds__(256, 2) void mlp_kernel(
    const float* __restrict__ x, const unsigned short* __restrict__ W1f,
    const float* __restrict__ b1, const unsigned short* __restrict__ W2f,
    const float* __restrict__ b2, const float* __restrict__ s,
    unsigned* __restrict__ hpack, float* __restrict__ sigbuf, int n)
{
    // LDS overlay: [0,32768)        B2L [4][8][64][8] h1^T frags (GEMM2 phase)
    //              [32768, +8192)   BX  [2][4][64][8] x frags (GEMM1 dbuf)
    //              [32768, +17408)  H0L [64][68] f32 (epilogue, after BX dead)
    //              [50176, +256)    SIGL[64] f32
    __shared__ __align__(16) char smem[50432];
    short* B2L  = (short*)smem;
    short* BX   = (short*)(smem + 32768);
    float* H0L  = (float*)(smem + 32768);
    float* SIGL = (float*)(smem + 50176);

    const int t  = threadIdx.x;
    const int w  = t >> 6, lz = t & 63;
    const int row0 = blockIdx.x * 64;

    const int srow = t >> 2;
    int xrow = row0 + srow; if (xrow >= n) xrow = n - 1;
    const float4* xp = (const float4*)(x + (size_t)xrow * NIN);
    const int q4a = t & 3, q4b = (t & 3) + 4;

    f32x4 acc[4][4];
    #pragma unroll
    for (int a = 0; a < 4; ++a)
        #pragma unroll
        for (int b = 0; b < 4; ++b) acc[a][b] = (f32x4)(0.f);

    auto xwrite = [&](int b, float4 va, float4 vb) {
        unsigned long long pa = (unsigned long long)pk2(va.x, va.y)
                              | ((unsigned long long)pk2(va.z, va.w) << 32);
        unsigned long long pb = (unsigned long long)pk2(vb.x, vb.y)
                              | ((unsigned long long)pk2(vb.z, vb.w) << 32);
        *(unsigned long long*)&BX[(((((b << 2) + (srow >> 4)) << 6)
            + ((srow & 15) | ((q4a >> 1) << 4))) << 3) + ((q4a & 1) << 2)] = pa;
        *(unsigned long long*)&BX[(((((b << 2) + (srow >> 4)) << 6)
            + ((srow & 15) | ((q4b >> 1) << 4))) << 3) + ((q4b & 1) << 2)] = pb;
    };
    auto compute = [&](int b, int kt) {
        bf16x8 xf[4], wf[4];
        #pragma unroll
        for (int nfn = 0; nfn < 4; ++nfn)
            xf[nfn] = *(const bf16x8*)&BX[((((b << 2) + nfn) << 6) + lz) << 3];
        const unsigned short* wp = W1f + ((size_t)kt << 13) + (w << 11) + (lz << 3);
        #pragma unroll
        for (int hf = 0; hf < 4; ++hf)
            wf[hf] = *(const bf16x8*)(wp + (hf << 9));
        #pragma unroll
        for (int nfn = 0; nfn < 4; ++nfn)
            #pragma unroll
            for (int hf = 0; hf < 4; ++hf)
                acc[nfn][hf] = __builtin_amdgcn_mfma_f32_16x16x32_bf16(
                    wf[hf], xf[nfn], acc[nfn][hf], 0, 0, 0);
    };

    {
        float4 xa = xp[q4a], xb = xp[q4b];
        xwrite(0, xa, xb);
    }
    __syncthreads();

    #pragma unroll 1
    for (int kt = 0; kt < 16; ++kt) {
        const int b = kt & 1;
        float4 nxa, nxb;
        if (kt < 15) {
            nxa = xp[((kt + 1) << 3) + q4a];
            nxb = xp[((kt + 1) << 3) + q4b];
        }
        compute(b, kt);
        if (kt < 15) xwrite(b ^ 1, nxa, nxb);
        __syncthreads();
    }

    // ---- bias + relu + in-register repack -> B2L (h1^T B-fragments) -----
    {
        float4 b1q[4];
        #pragma unroll
        for (int hf = 0; hf < 4; ++hf)
            b1q[hf] = *(const float4*)(b1 + (w << 6) + (hf << 4) + ((lz >> 4) << 2));
        #pragma unroll
        for (int nfn = 0; nfn < 4; ++nfn) {
            #pragma unroll
            for (int cl = 0; cl < 2; ++cl) {
                f32x4 a0 = acc[nfn][2 * cl], a1 = acc[nfn][2 * cl + 1];
                float4 c0 = b1q[2 * cl], c1 = b1q[2 * cl + 1];
                uint4 pv;
                pv.x = pk2(fmaxf(a0.x + c0.x, 0.f), fmaxf(a0.y + c0.y, 0.f));
                pv.y = pk2(fmaxf(a0.z + c0.z, 0.f), fmaxf(a0.w + c0.w, 0.f));
                pv.z = pk2(fmaxf(a1.x + c1.x, 0.f), fmaxf(a1.y + c1.y, 0.f));
                pv.w = pk2(fmaxf(a1.z + c1.z, 0.f), fmaxf(a1.w + c1.w, 0.f));
                *(uint4*)&B2L[((((nfn << 3) + (w << 1) + cl) << 6) + lz) << 3] = pv;
            }
        }
    }
    __syncthreads();

    // ---- GEMM2: h0^T = W2 @ h1^T ----------------------------------------
    f32x4 acc2[4];
    #pragma unroll
    for (int nf2 = 0; nf2 < 4; ++nf2) acc2[nf2] = (f32x4)(0.f);

    #pragma unroll
    for (int c = 0; c < 8; ++c) {
        bf16x8 hfrag = *(const bf16x8*)&B2L[((((w << 3) + c) << 6) + lz) << 3];
        #pragma unroll
        for (int nf2 = 0; nf2 < 4; ++nf2) {
            bf16x8 wfrag = *(const bf16x8*)(W2f + (((c << 2) + nf2) << 9) + (lz << 3));
            acc2[nf2] = __builtin_amdgcn_mfma_f32_16x16x32_bf16(
                wfrag, hfrag, acc2[nf2], 0, 0, 0);
        }
    }

    // ---- epilogue: bias, attention dot, sigmoid, LDS reshape, stores -----
    {
        float dot = 0.f;
        #pragma unroll
        for (int nf2 = 0; nf2 < 4; ++nf2) {
            float4 bq = *(const float4*)(b2 + (nf2 << 4) + ((lz >> 4) << 2));
            float4 qv = *(const float4*)(s  + (nf2 << 4) + ((lz >> 4) << 2));
            acc2[nf2].x += bq.x; acc2[nf2].y += bq.y;
            acc2[nf2].z += bq.z; acc2[nf2].w += bq.w;
            dot += acc2[nf2].x * qv.x + acc2[nf2].y * qv.y
                 + acc2[nf2].z * qv.z + acc2[nf2].w * qv.w;
        }
        dot += __shfl_xor(dot, 16);
        dot += __shfl_xor(dot, 32);
        const float sig = 1.f / (1.f + expf(-dot));
        if (lz < 16) SIGL[(w << 4) + lz] = sig;
        const int mloc = (w << 4) + (lz & 15);
        #pragma unroll
        for (int nf2 = 0; nf2 < 4; ++nf2) {
            float4 hv; hv.x = acc2[nf2].x; hv.y = acc2[nf2].y;
            hv.z = acc2[nf2].z; hv.w = acc2[nf2].w;
            *(float4*)&H0L[mloc * 68 + (nf2 << 4) + ((lz >> 4) << 2)] = hv;
        }
    }
    __syncthreads();

    {
        const int m = t >> 2, q = t & 3;
        const int g = row0 + m;
        if (g < n) {
            unsigned* hp = hpack + (size_t)g * 32 + (q << 3);
            #pragma unroll
            for (int i = 0; i < 16; i += 4) {
                float4 hv = *(const float4*)&H0L[m * 68 + (q << 4) + i];
                uint2 pv;
                pv.x = pk2(hv.x, hv.y);
                pv.y = pk2(hv.z, hv.w);
                *(uint2*)(hp + (i >> 1)) = pv;
            }
        }
        if (t < 64 && row0 + t < n) sigbuf[row0 + t] = SIGL[t];
    }
}

// ---------------------------------------------------------------------------
// CSR build: degree count -> hierarchical exclusive scan -> scatter (packed)
// ---------------------------------------------------------------------------
__global__ void k_count(const int* __restrict__ erow, int* __restrict__ deg, int e) {
    int i = blockIdx.x * 256 + threadIdx.x;
    if (i < e) atomicAdd(&deg[erow[i]], 1);
}

__global__ void k_scan1(const int* __restrict__ deg, int* __restrict__ rp,
                        int* __restrict__ bsum, int nv) {
    __shared__ int sm[256];
    const int i = blockIdx.x * 256 + threadIdx.x;
    const int v = (i < nv) ? deg[i] : 0;
    sm[threadIdx.x] = v;
    __syncthreads();
    for (int off = 1; off < 256; off <<= 1) {
        int tv = (threadIdx.x >= off) ? sm[threadIdx.x - off] : 0;
        __syncthreads();
        sm[threadIdx.x] += tv;
        __syncthreads();
    }
    if (i < nv) rp[i] = sm[threadIdx.x] - v;
    if (threadIdx.x == 255) bsum[blockIdx.x] = sm[255];
}

__global__ void k_scan2(int* __restrict__ bsum, int nb) {
    __shared__ int sm[512];
    const int tid = threadIdx.x;
    const int v = (tid < nb) ? bsum[tid] : 0;
    sm[tid] = v;
    __syncthreads();
    for (int off = 1; off < 512; off <<= 1) {
        int tv = (tid >= off) ? sm[tid - off] : 0;
        __syncthreads();
        sm[tid] += tv;
        __syncthreads();
    }
    if (tid < nb) bsum[tid] = sm[tid] - v;
}

__global__ void k_scan3(int* __restrict__ rp, int* __restrict__ cur,
                        const int* __restrict__ bsum, int nv, int e) {
    const int i = blockIdx.x * 256 + threadIdx.x;
    if (i < nv) {
        const int vv = rp[i] + bsum[blockIdx.x];
        rp[i]  = vv;
        cur[i] = vv;
    }
    if (i == 0) rp[nv] = e;
}

__global__ void k_scatter(const int* __restrict__ erow, const int* __restrict__ ecol,
                          const float* __restrict__ ev, int* __restrict__ cur,
                          unsigned long long* __restrict__ cpack, int e) {
    const int i = blockIdx.x * 256 + threadIdx.x;
    if (i < e) {
        const int r = erow[i];
        const int p = atomicAdd(&cur[r], 1);
        cpack[p] = ((unsigned long long)__float_as_uint(ev[i]) << 32)
                 | (unsigned)ecol[i];
    }
}

// ---------------------------------------------------------------------------
// One propagation hop (pull, CSR, bf16-packed h). 32 lanes = 1 node (2
// features/lane). Writes h_out (bf16 pairs) + sig scalar; out deferred.
// ---------------------------------------------------------------------------
__global__ __launch_bounds__(256) void hop_kernel(
    const unsigned* __restrict__ h_in, unsigned* __restrict__ h_out,
    const int* __restrict__ row_ptr, const unsigned long long* __restrict__ cpack,
    const float* __restrict__ s, float* __restrict__ sig_out, int n)
{
    const int t  = threadIdx.x;
    const int sl = t & 31;
    const int node = (blockIdx.x * 256 + t) >> 5;
    if (node >= n) return;
    const int start = row_ptr[node];
    const int end   = row_ptr[node + 1];
    float a0 = 0.f, a1 = 0.f;
    for (int base = start; base < end; base += 32) {
        const int idx = base + sl;
        unsigned long long pc = (idx < end) ? cpack[idx] : 0ULL;
        int   c = (int)(unsigned)pc;
        float v = __uint_as_float((unsigned)(pc >> 32));
        const int cnt = min(32, end - base);
        int e = 0;
        for (; e + 4 <= cnt; e += 4) {           // 4 gathers in flight
            int   c0 = __shfl(c, e, 32),     c1 = __shfl(c, e + 1, 32);
            int   c2 = __shfl(c, e + 2, 32), c3 = __shfl(c, e + 3, 32);
            float v0 = __shfl(v, e, 32),     v1 = __shfl(v, e + 1, 32);
            float v2 = __shfl(v, e + 2, 32), v3 = __shfl(v, e + 3, 32);
            unsigned g0 = h_in[(size_t)c0 * 32 + sl];
            unsigned g1 = h_in[(size_t)c1 * 32 + sl];
            unsigned g2 = h_in[(size_t)c2 * 32 + sl];
            unsigned g3 = h_in[(size_t)c3 * 32 + sl];
            a0 = fmaf(v0, bflo(g0), a0); a1 = fmaf(v0, bfhi(g0), a1);
            a0 = fmaf(v1, bflo(g1), a0); a1 = fmaf(v1, bfhi(g1), a1);
            a0 = fmaf(v2, bflo(g2), a0); a1 = fmaf(v2, bfhi(g2), a1);
            a0 = fmaf(v3, bflo(g3), a0); a1 = fmaf(v3, bfhi(g3), a1);
        }
        for (; e < cnt; ++e) {
            int   cc = __shfl(c, e, 32);
            float vv = __shfl(v, e, 32);
            unsigned g = h_in[(size_t)cc * 32 + sl];
            a0 = fmaf(vv, bflo(g), a0); a1 = fmaf(vv, bfhi(g), a1);
        }
    }
    const float2 sv = ((const float2*)s)[sl];
    float tv = a0 * sv.x + a1 * sv.y;
    #pragma unroll
    for (int off = 16; off > 0; off >>= 1) tv += __shfl_xor(tv, off, 32);
    h_out[(size_t)node * 32 + sl] = pk2(a0, a1);
    if (sl == 0) sig_out[node] = 1.f / (1.f + expf(-tv));
}

// ---------------------------------------------------------------------------
// Final combine: out[n][64] = sum_k sig_k(n) * h_k(n)   (fp32 output)
// ---------------------------------------------------------------------------
__global__ __launch_bounds__(256) void k_combine(
    const unsigned* __restrict__ hbuf, const float* __restrict__ sigbuf,
    float* __restrict__ out, int n)
{
    const int gid  = blockIdx.x * 256 + threadIdx.x;
    const int node = gid >> 5, sl = gid & 31;
    if (node >= n) return;
    float o0 = 0.f, o1 = 0.f;
    #pragma unroll
    for (int k = 0; k <= HOPS; ++k) {
        const unsigned g = hbuf[(size_t)k * n * 32 + (size_t)node * 32 + sl];
        const float sg = sigbuf[(size_t)k * n + node];
        o0 = fmaf(sg, bflo(g), o0);
        o1 = fmaf(sg, bfhi(g), o1);
    }
    float2 ov; ov.x = o0; ov.y = o1;
    ((float2*)out)[(size_t)node * 32 + sl] = ov;
}

// ---------------------------------------------------------------------------
extern "C" void kernel_launch(void* const* d_in, const int* in_sizes, int n_in,
                              void* d_out, int out_size, void* d_ws, size_t ws_size,
                              hipStream_t stream)
{
    const float* x  = (const float*)d_in[0];
    const int*   er = (const int*)  d_in[1];
    const int*   ec = (const int*)  d_in[2];
    const float* ev = (const float*)d_in[3];
    const float* W1 = (const float*)d_in[4];
    const float* b1 = (const float*)d_in[5];
    const float* W2 = (const float*)d_in[6];
    const float* b2 = (const float*)d_in[7];
    const float* s  = (const float*)d_in[8];
    float* out = (float*)d_out;

    const int n = in_sizes[0] / NIN;   // 100000
    const int e = in_sizes[1];         // 1600000

    // workspace carve (256B aligned): ~160 MB of the ~800 MB ws
    char* w = (char*)d_ws;
    auto carve = [&](size_t bytes) { char* p = w; w += (bytes + 255) & ~(size_t)255; return p; };
    unsigned* hbuf   = (unsigned*)carve((size_t)(HOPS + 1) * n * 32 * 4);  // 140.8 MB
    float*    sigbuf = (float*)   carve((size_t)(HOPS + 1) * n * 4);       // 4.4 MB
    int*      deg    = (int*)     carve((size_t)n * 4);
    int*      rp     = (int*)     carve(((size_t)n + 1) * 4);
    int*      cur    = (int*)     carve((size_t)n * 4);
    unsigned long long* cpack = (unsigned long long*)carve((size_t)e * 8); // 12.8 MB
    int*      bsum   = (int*)     carve(1024 * 4);
    unsigned short* W1f = (unsigned short*)carve((size_t)NHID * NIN * 2);
    unsigned short* W2f = (unsigned short*)carve((size_t)NOUT * NHID * 2);

    hipMemsetAsync(deg, 0, (size_t)n * 4, stream);

    k_preconv<<<(NHID * NIN + 255) / 256, 256, 0, stream>>>(W1, W2, W1f, W2f);

    const int mgrid = (n + 63) / 64;
    mlp_kernel<<<mgrid, 256, 0, stream>>>(x, W1f, b1, W2f, b2, s,
                                          hbuf, sigbuf, n);

    const int eg = (e + 255) / 256;
    const int nb = (n + 255) / 256;
    k_count  <<<eg, 256, 0, stream>>>(er, deg, e);
    k_scan1  <<<nb, 256, 0, stream>>>(deg, rp, bsum, n);
    k_scan2  <<<1, 512, 0, stream>>>(bsum, nb);
    k_scan3  <<<nb, 256, 0, stream>>>(rp, cur, bsum, n, e);
    k_scatter<<<eg, 256, 0, stream>>>(er, ec, ev, cur, cpack, e);

    const int hgrid = ((size_t)n * 32 + 255) / 256;
    for (int hop = 0; hop < HOPS; ++hop) {
        hop_kernel<<<hgrid, 256, 0, stream>>>(
            hbuf + (size_t)hop * n * 32, hbuf + (size_t)(hop + 1) * n * 32,
            rp, cpack, s, sigbuf + (size_t)(hop + 1) * n, n);
    }

    k_combine<<<hgrid, 256, 0, stream>>>(hbuf, sigbuf, out, n);
}